// Round 1
// baseline (997.905 us; speedup 1.0000x reference)
//
#include <hip/hip_runtime.h>
#include <hip/hip_bf16.h>

// GraphSAGE 2-layer, N=100K nodes, E=1.6M edges, 128->128(relu)->64, log_softmax.
// Strategy: build CSR-ish segments once (int atomics only), reuse for both layers.
// Aggregation = wave-per-node gather (feature table is L3-resident: 51.2MB < 256MB).
// GEMMs = fused dual-matmul (agg@Wl + x@Wr + b) on vector ALU (no fp32 MFMA on CDNA4).

__global__ void hist_kernel(const int* __restrict__ dst, int* __restrict__ deg, int E) {
    int e = blockIdx.x * blockDim.x + threadIdx.x;
    if (e < E) atomicAdd(&deg[dst[e]], 1);
}

// Assign disjoint segments [s, s+deg) in arbitrary order (sum per node is order-independent).
__global__ void assign_kernel(const int* __restrict__ deg, int* __restrict__ total,
                              int* __restrict__ row_start, int* __restrict__ cursor,
                              float* __restrict__ inv_deg, int N) {
    int n = blockIdx.x * blockDim.x + threadIdx.x;
    if (n < N) {
        int d = deg[n];
        int s = atomicAdd(total, d);
        row_start[n] = s;
        cursor[n] = s;
        inv_deg[n] = 1.0f / (float)(d > 1 ? d : 1);
    }
}

__global__ void fill_kernel(const int* __restrict__ src, const int* __restrict__ dst,
                            int* __restrict__ cursor, int* __restrict__ ssrc, int E) {
    int e = blockIdx.x * blockDim.x + threadIdx.x;
    if (e < E) {
        int p = atomicAdd(&cursor[dst[e]], 1);
        ssrc[p] = src[e];
    }
}

// One wave per node; lane l holds float2 (features 2l, 2l+1) of the 128-wide row.
__global__ void aggregate_kernel(const float* __restrict__ feat,
                                 const int* __restrict__ ssrc,
                                 const int* __restrict__ row_start,
                                 const int* __restrict__ deg,
                                 const float* __restrict__ inv_deg,
                                 float* __restrict__ agg, int N) {
    int wave = threadIdx.x >> 6;
    int lane = threadIdx.x & 63;
    int n = blockIdx.x * 4 + wave;
    if (n >= N) return;
    int start = row_start[n];
    int d = deg[n];
    const int* sp = ssrc + start;
    float ax = 0.f, ay = 0.f;
    int j = 0;
    for (; j + 4 <= d; j += 4) {  // 4 independent row loads in flight per iter
        int s0 = sp[j + 0], s1 = sp[j + 1], s2 = sp[j + 2], s3 = sp[j + 3];
        float2 v0 = ((const float2*)(feat + (long)s0 * 128))[lane];
        float2 v1 = ((const float2*)(feat + (long)s1 * 128))[lane];
        float2 v2 = ((const float2*)(feat + (long)s2 * 128))[lane];
        float2 v3 = ((const float2*)(feat + (long)s3 * 128))[lane];
        ax += (v0.x + v1.x) + (v2.x + v3.x);
        ay += (v0.y + v1.y) + (v2.y + v3.y);
    }
    for (; j < d; ++j) {
        float2 v = ((const float2*)(feat + (long)sp[j] * 128))[lane];
        ax += v.x; ay += v.y;
    }
    float iv = inv_deg[n];
    float2 o; o.x = ax * iv; o.y = ay * iv;
    ((float2*)(agg + (long)n * 128))[lane] = o;
}

// out[r][c] = sum_k A[r][k]*Wl[k][c] + X[r][k]*Wr[k][c] + b[c], optional relu.
// 64 rows per block; each thread computes 8 rows x 4 cols.
template <int COLS, bool RELU>
__global__ void gemm_dual(const float* __restrict__ A, const float* __restrict__ X,
                          const float* __restrict__ Wl, const float* __restrict__ Wr,
                          const float* __restrict__ bias, float* __restrict__ out,
                          int nrows) {
    constexpr int ROWS = 64;
    constexpr int CG = COLS / 4;      // column groups (4 cols each)
    constexpr int RG = ROWS / 8;      // row groups (8 rows each)
    constexpr int NT = CG * RG;       // threads per block
    __shared__ float sA[ROWS][128];
    __shared__ float sX[ROWS][128];
    int tid = threadIdx.x;
    long row0 = (long)blockIdx.x * ROWS;

    // Stage 64x128 tiles of A and X (coalesced float4).
    for (int i = tid; i < ROWS * 128 / 4; i += NT) {
        int r = i >> 5;       // /32 float4 per row
        int kc = i & 31;
        long gr = row0 + r;
        float4 va = make_float4(0.f, 0.f, 0.f, 0.f), vx = va;
        if (gr < nrows) {
            va = ((const float4*)(A + gr * 128))[kc];
            vx = ((const float4*)(X + gr * 128))[kc];
        }
        ((float4*)&sA[r][0])[kc] = va;
        ((float4*)&sX[r][0])[kc] = vx;
    }
    __syncthreads();

    int cg = tid % CG, rg = tid / CG;
    int c0 = cg * 4, r0 = rg * 8;
    float acc[8][4] = {};
#pragma unroll 4
    for (int k = 0; k < 128; ++k) {
        float4 wl = *(const float4*)(Wl + (long)k * COLS + c0);
        float4 wr = *(const float4*)(Wr + (long)k * COLS + c0);
#pragma unroll
        for (int r = 0; r < 8; ++r) {
            float a = sA[r0 + r][k];   // same-address broadcast within half-wave
            float xv = sX[r0 + r][k];
            acc[r][0] += a * wl.x + xv * wr.x;
            acc[r][1] += a * wl.y + xv * wr.y;
            acc[r][2] += a * wl.z + xv * wr.z;
            acc[r][3] += a * wl.w + xv * wr.w;
        }
    }

    float4 bv = *(const float4*)(bias + c0);
#pragma unroll
    for (int r = 0; r < 8; ++r) {
        long gr = row0 + r0 + r;
        if (gr < nrows) {
            float4 o;
            o.x = acc[r][0] + bv.x; o.y = acc[r][1] + bv.y;
            o.z = acc[r][2] + bv.z; o.w = acc[r][3] + bv.w;
            if (RELU) {
                o.x = fmaxf(o.x, 0.f); o.y = fmaxf(o.y, 0.f);
                o.z = fmaxf(o.z, 0.f); o.w = fmaxf(o.w, 0.f);
            }
            *(float4*)(out + gr * COLS + c0) = o;
        }
    }
}

// In-place log_softmax over rows of 64; one wave per row, lane = class.
__global__ void logsoftmax_kernel(float* __restrict__ out, int N) {
    int wave = threadIdx.x >> 6;
    int lane = threadIdx.x & 63;
    int n = blockIdx.x * 4 + wave;
    if (n >= N) return;
    float z = out[(long)n * 64 + lane];
    float m = z;
#pragma unroll
    for (int o = 32; o > 0; o >>= 1) m = fmaxf(m, __shfl_xor(m, o));
    float e = __expf(z - m);
    float s = e;
#pragma unroll
    for (int o = 32; o > 0; o >>= 1) s += __shfl_xor(s, o);
    out[(long)n * 64 + lane] = z - m - __logf(s);
}

extern "C" void kernel_launch(void* const* d_in, const int* in_sizes, int n_in,
                              void* d_out, int out_size, void* d_ws, size_t ws_size,
                              hipStream_t stream) {
    const float* x   = (const float*)d_in[0];
    const int*   ei  = (const int*)d_in[1];
    const float* Wl1 = (const float*)d_in[2];
    const float* Wr1 = (const float*)d_in[3];
    const float* b1  = (const float*)d_in[4];
    const float* Wl2 = (const float*)d_in[5];
    const float* Wr2 = (const float*)d_in[6];
    const float* b2  = (const float*)d_in[7];

    const int N = in_sizes[0] / 128;
    const int E = in_sizes[1] / 2;
    const int* src = ei;       // edge_index[0]
    const int* dst = ei + E;   // edge_index[1]

    // Workspace carve-up (256B-aligned chunks). Total ~110 MB.
    size_t off = 0;
    auto take = [&](size_t nbytes) -> void* {
        void* p = (void*)((char*)d_ws + off);
        off += (nbytes + 255) & ~(size_t)255;
        return p;
    };
    int*   deg       = (int*)take((size_t)(N + 1) * 4);  // deg[N] + total[1]
    int*   total     = deg + N;
    float* inv_deg   = (float*)take((size_t)N * 4);
    int*   row_start = (int*)take((size_t)N * 4);
    int*   cursor    = (int*)take((size_t)N * 4);
    int*   ssrc      = (int*)take((size_t)E * 4);
    float* agg       = (float*)take((size_t)N * 128 * 4);
    float* h         = (float*)take((size_t)N * 128 * 4);
    (void)ws_size; (void)n_in; (void)out_size;

    hipMemsetAsync(deg, 0, (size_t)(N + 1) * 4, stream);

    hist_kernel<<<(E + 255) / 256, 256, 0, stream>>>(dst, deg, E);
    assign_kernel<<<(N + 255) / 256, 256, 0, stream>>>(deg, total, row_start, cursor, inv_deg, N);
    fill_kernel<<<(E + 255) / 256, 256, 0, stream>>>(src, dst, cursor, ssrc, E);

    // Layer 1: agg = mean_nbr(x); h = relu(agg@Wl1 + x@Wr1 + b1)
    aggregate_kernel<<<(N + 3) / 4, 256, 0, stream>>>(x, ssrc, row_start, deg, inv_deg, agg, N);
    gemm_dual<128, true><<<(N + 63) / 64, 256, 0, stream>>>(agg, x, Wl1, Wr1, b1, h, N);

    // Layer 2: agg = mean_nbr(h); z = agg@Wl2 + h@Wr2 + b2
    aggregate_kernel<<<(N + 3) / 4, 256, 0, stream>>>(h, ssrc, row_start, deg, inv_deg, agg, N);
    gemm_dual<64, false><<<(N + 63) / 64, 128, 0, stream>>>(agg, h, Wl2, Wr2, b2, (float*)d_out, N);

    logsoftmax_kernel<<<(N + 3) / 4, 256, 0, stream>>>((float*)d_out, N);
}

// Round 2
// 512.238 us; speedup vs baseline: 1.9481x; 1.9481x over previous
//
#include <hip/hip_runtime.h>
#include <hip/hip_bf16.h>

// GraphSAGE 2-layer, N=100K, E=1.6M, 128->128(relu)->64, log_softmax. fp32 in/out.
//
// Restructured via linearity of aggregation: mean_nbr(x) @ W == mean_nbr(x @ W).
//   p = bf16(x@Wl1); q = x@Wr1 + b1          (MFMA proj, one input read)
//   h = bf16(relu(mean_nbr(p) + q))           (gather p: 410MB bf16, fused epilogue)
//   u = bf16(h@Wl2); v = h@Wr2 + b2           (MFMA proj)
//   out = log_softmax(mean_nbr(u) + v)        (gather u: 102MB bf16, fused epilogue)
// GEMMs use mfma_f32_16x16x32_bf16 (no fp32 MFMA on CDNA4); tolerance (~2% of ref
// absmax 5.78) comfortably covers bf16 rounding (~2e-3 abs here).

typedef __attribute__((ext_vector_type(8))) short short8;   // 8 x bf16 = 4 VGPRs
typedef __attribute__((ext_vector_type(4))) float f32x4;

__device__ __forceinline__ ushort f2bf(float f) {           // round-to-nearest-even
    unsigned u = __float_as_uint(f);
    return (ushort)((u + 0x7fff + ((u >> 16) & 1)) >> 16);
}
__device__ __forceinline__ float bflo(unsigned v) { return __uint_as_float(v << 16); }
__device__ __forceinline__ float bfhi(unsigned v) { return __uint_as_float(v & 0xffff0000u); }

// ---------------- graph setup (int atomics only, built once, reused twice) ---------
__global__ void hist_kernel(const int* __restrict__ dst, int* __restrict__ deg, int E) {
    int e = blockIdx.x * blockDim.x + threadIdx.x;
    if (e < E) atomicAdd(&deg[dst[e]], 1);
}

__global__ void assign_kernel(const int* __restrict__ deg, int* __restrict__ total,
                              int* __restrict__ row_start, int* __restrict__ cursor,
                              float* __restrict__ inv_deg, int N) {
    int n = blockIdx.x * blockDim.x + threadIdx.x;
    if (n < N) {
        int d = deg[n];
        int s = atomicAdd(total, d);
        row_start[n] = s;
        cursor[n] = s;
        inv_deg[n] = 1.0f / (float)(d > 1 ? d : 1);
    }
}

__global__ void fill_kernel(const int* __restrict__ src, const int* __restrict__ dst,
                            int* __restrict__ cursor, int* __restrict__ ssrc, int E) {
    int e = blockIdx.x * blockDim.x + threadIdx.x;
    if (e < E) {
        int p = atomicAdd(&cursor[dst[e]], 1);
        ssrc[p] = src[e];
    }
}

// ---------------- dtype conversions ------------------------------------------------
__global__ void cvt_x_kernel(const float* __restrict__ x, ushort* __restrict__ xb, long n4) {
    long i = (long)blockIdx.x * blockDim.x + threadIdx.x;
    if (i >= n4) return;
    float4 v = ((const float4*)x)[i];
    ushort4 o;
    o.x = f2bf(v.x); o.y = f2bf(v.y); o.z = f2bf(v.z); o.w = f2bf(v.w);
    ((ushort4*)xb)[i] = o;
}

// Repack all four weight matrices into bf16 MFMA B-fragment order:
//   idx = ((ct*16 + kc)*16 + m)*8 + j  holds  W[k= kc*8+j][c= ct*16+m]
// so a wave's B-frag load (16B/lane) is fully contiguous/coalesced.
__device__ __forceinline__ void wfrag_one(const float* W, ushort* Wf, int i, int COLS) {
    int j  = i & 7;
    int m  = (i >> 3) & 15;
    int kc = (i >> 7) & 15;
    int ct = i >> 11;
    int c = ct * 16 + m;
    int k = kc * 8 + j;
    Wf[i] = f2bf(W[k * COLS + c]);
}
__global__ void cvt_w_kernel(const float* __restrict__ Wl1, const float* __restrict__ Wr1,
                             const float* __restrict__ Wl2, const float* __restrict__ Wr2,
                             ushort* __restrict__ Wf_l1, ushort* __restrict__ Wf_r1,
                             ushort* __restrict__ Wf_l2, ushort* __restrict__ Wf_r2) {
    int i = blockIdx.x * blockDim.x + threadIdx.x;   // 49152 total
    if (i < 16384)       wfrag_one(Wl1, Wf_l1, i, 128);
    else if (i < 32768)  wfrag_one(Wr1, Wf_r1, i - 16384, 128);
    else if (i < 40960)  wfrag_one(Wl2, Wf_l2, i - 32768, 64);
    else if (i < 49152)  wfrag_one(Wr2, Wf_r2, i - 40960, 64);
}

// ---------------- dual projection: p = bf16(X@Wl), q = X@Wr + b --------------------
// Block = 4 waves; each wave owns a 16-row stripe, all COLS columns. K=128.
// A-frag: A[m=lane&15][k=quad*8+j] -> 16B contiguous from bf16 row (no LDS needed).
// B-frag: fragment-order layout above -> 16B contiguous, wave-coalesced, L1-resident.
// C/D: col = lane&15, row = quad*4 + reg   [verified mapping, learn_hip m89/m91]
template <int COLS>
__global__ void proj_kernel(const ushort* __restrict__ xb,      // N x 128 bf16
                            const ushort* __restrict__ Wfl,     // COLS*128 frag-order
                            const ushort* __restrict__ Wfr,
                            const float* __restrict__ bias,     // COLS
                            ushort* __restrict__ p,             // N x COLS bf16
                            float* __restrict__ q,              // N x COLS f32
                            int N) {
    constexpr int CT = COLS / 16;
    int wave = threadIdx.x >> 6, lane = threadIdx.x & 63;
    int quad = lane >> 4, m = lane & 15;
    long row0 = (long)blockIdx.x * 64 + wave * 16;
    long arow = row0 + m;
    if (arow >= N) arow = N - 1;                    // clamped load; store is guarded

    f32x4 accp[CT], accq[CT];
#pragma unroll
    for (int ct = 0; ct < CT; ++ct) { accp[ct] = (f32x4)0.0f; accq[ct] = (f32x4)0.0f; }

#pragma unroll
    for (int kk = 0; kk < 128; kk += 32) {
        short8 a = *(const short8*)(xb + arow * 128 + kk + quad * 8);
        int kc = (kk >> 3) + quad;
#pragma unroll
        for (int ct = 0; ct < CT; ++ct) {
            long boff = (((long)(ct * 16 + kc) * 16) + m) * 8;
            short8 bl = *(const short8*)(Wfl + boff);
            short8 br = *(const short8*)(Wfr + boff);
            accp[ct] = __builtin_amdgcn_mfma_f32_16x16x32_bf16(a, bl, accp[ct], 0, 0, 0);
            accq[ct] = __builtin_amdgcn_mfma_f32_16x16x32_bf16(a, br, accq[ct], 0, 0, 0);
        }
    }

#pragma unroll
    for (int ct = 0; ct < CT; ++ct) {
        int col = ct * 16 + m;
        float bv = bias[col];
#pragma unroll
        for (int r = 0; r < 4; ++r) {
            long row = row0 + quad * 4 + r;
            if (row < N) {
                p[row * COLS + col] = f2bf(accp[ct][r]);
                q[row * COLS + col] = accq[ct][r] + bv;
            }
        }
    }
}

// ---------------- layer-1 aggregate: h = bf16(relu(mean_nbr(p) + q)) ---------------
// One wave per node; lane holds cols (2l, 2l+1) as one bf16x2 dword.
__global__ void agg_relu_kernel(const ushort* __restrict__ p,    // N x 128 bf16
                                const float* __restrict__ q,     // N x 128 f32
                                const int* __restrict__ ssrc,
                                const int* __restrict__ row_start,
                                const int* __restrict__ deg,
                                const float* __restrict__ inv_deg,
                                ushort* __restrict__ hb, int N) {
    int wave = threadIdx.x >> 6, lane = threadIdx.x & 63;
    int n = blockIdx.x * 4 + wave;
    if (n >= N) return;
    int start = row_start[n], d = deg[n];
    const int* sp = ssrc + start;
    float ax = 0.f, ay = 0.f;
    int j = 0;
    for (; j + 4 <= d; j += 4) {       // 4 independent gathers in flight
        int s0 = sp[j], s1 = sp[j + 1], s2 = sp[j + 2], s3 = sp[j + 3];
        unsigned v0 = ((const unsigned*)(p + (long)s0 * 128))[lane];
        unsigned v1 = ((const unsigned*)(p + (long)s1 * 128))[lane];
        unsigned v2 = ((const unsigned*)(p + (long)s2 * 128))[lane];
        unsigned v3 = ((const unsigned*)(p + (long)s3 * 128))[lane];
        ax += (bflo(v0) + bflo(v1)) + (bflo(v2) + bflo(v3));
        ay += (bfhi(v0) + bfhi(v1)) + (bfhi(v2) + bfhi(v3));
    }
    for (; j < d; ++j) {
        unsigned v = ((const unsigned*)(p + (long)sp[j] * 128))[lane];
        ax += bflo(v); ay += bfhi(v);
    }
    float iv = inv_deg[n];
    float2 qv = ((const float2*)(q + (long)n * 128))[lane];
    float hx = fmaxf(ax * iv + qv.x, 0.f);
    float hy = fmaxf(ay * iv + qv.y, 0.f);
    ((unsigned*)(hb + (long)n * 128))[lane] = (unsigned)f2bf(hx) | ((unsigned)f2bf(hy) << 16);
}

// ---------------- layer-2 aggregate + log_softmax ----------------------------------
// One wave per node; lane = class (64). Gather u rows (128B, bf16), fused epilogue.
__global__ void agg_lsm_kernel(const ushort* __restrict__ u,     // N x 64 bf16
                               const float* __restrict__ v,      // N x 64 f32
                               const int* __restrict__ ssrc,
                               const int* __restrict__ row_start,
                               const int* __restrict__ deg,
                               const float* __restrict__ inv_deg,
                               float* __restrict__ out, int N) {
    int wave = threadIdx.x >> 6, lane = threadIdx.x & 63;
    int n = blockIdx.x * 4 + wave;
    if (n >= N) return;
    int start = row_start[n], d = deg[n];
    const int* sp = ssrc + start;
    float a = 0.f;
    int j = 0;
    for (; j + 4 <= d; j += 4) {
        int s0 = sp[j], s1 = sp[j + 1], s2 = sp[j + 2], s3 = sp[j + 3];
        float f0 = bflo((unsigned)u[(long)s0 * 64 + lane]);
        float f1 = bflo((unsigned)u[(long)s1 * 64 + lane]);
        float f2 = bflo((unsigned)u[(long)s2 * 64 + lane]);
        float f3 = bflo((unsigned)u[(long)s3 * 64 + lane]);
        a += (f0 + f1) + (f2 + f3);
    }
    for (; j < d; ++j) a += bflo((unsigned)u[(long)sp[j] * 64 + lane]);

    float z = a * inv_deg[n] + v[(long)n * 64 + lane];
    float mx = z;
#pragma unroll
    for (int o = 32; o > 0; o >>= 1) mx = fmaxf(mx, __shfl_xor(mx, o));
    float e = __expf(z - mx);
    float s = e;
#pragma unroll
    for (int o = 32; o > 0; o >>= 1) s += __shfl_xor(s, o);
    out[(long)n * 64 + lane] = z - mx - __logf(s);
}

// -----------------------------------------------------------------------------------
extern "C" void kernel_launch(void* const* d_in, const int* in_sizes, int n_in,
                              void* d_out, int out_size, void* d_ws, size_t ws_size,
                              hipStream_t stream) {
    const float* x   = (const float*)d_in[0];
    const int*   ei  = (const int*)d_in[1];
    const float* Wl1 = (const float*)d_in[2];
    const float* Wr1 = (const float*)d_in[3];
    const float* b1  = (const float*)d_in[4];
    const float* Wl2 = (const float*)d_in[5];
    const float* Wr2 = (const float*)d_in[6];
    const float* b2  = (const float*)d_in[7];

    const int N = in_sizes[0] / 128;
    const int E = in_sizes[1] / 2;
    const int* src = ei;
    const int* dst = ei + E;

    size_t off = 0;
    auto take = [&](size_t nbytes) -> void* {
        void* ptr = (void*)((char*)d_ws + off);
        off += (nbytes + 255) & ~(size_t)255;
        return ptr;
    };
    int*    deg       = (int*)take((size_t)(N + 1) * 4);
    int*    total     = deg + N;
    float*  inv_deg   = (float*)take((size_t)N * 4);
    int*    row_start = (int*)take((size_t)N * 4);
    int*    cursor    = (int*)take((size_t)N * 4);
    int*    ssrc      = (int*)take((size_t)E * 4);
    ushort* xb        = (ushort*)take((size_t)N * 128 * 2);  // also reused as hb
    ushort* p         = (ushort*)take((size_t)N * 128 * 2);  // also reused as u
    float*  q         = (float*)take((size_t)N * 128 * 4);   // also reused as v
    ushort* Wf_l1     = (ushort*)take(128 * 128 * 2);
    ushort* Wf_r1     = (ushort*)take(128 * 128 * 2);
    ushort* Wf_l2     = (ushort*)take(64 * 128 * 2);
    ushort* Wf_r2     = (ushort*)take(64 * 128 * 2);
    ushort* hb = xb;   // x dead after proj1
    ushort* u  = p;    // p dead after agg1
    float*  v  = q;    // q dead after agg1
    (void)ws_size; (void)n_in; (void)out_size;

    hipMemsetAsync(deg, 0, (size_t)(N + 1) * 4, stream);

    hist_kernel  <<<(E + 255) / 256, 256, 0, stream>>>(dst, deg, E);
    assign_kernel<<<(N + 255) / 256, 256, 0, stream>>>(deg, total, row_start, cursor, inv_deg, N);
    fill_kernel  <<<(E + 255) / 256, 256, 0, stream>>>(src, dst, cursor, ssrc, E);

    long n4 = (long)N * 128 / 4;
    cvt_x_kernel<<<(int)((n4 + 255) / 256), 256, 0, stream>>>(x, xb, n4);
    cvt_w_kernel<<<192, 256, 0, stream>>>(Wl1, Wr1, Wl2, Wr2, Wf_l1, Wf_r1, Wf_l2, Wf_r2);

    // layer 1
    proj_kernel<128><<<(N + 63) / 64, 256, 0, stream>>>(xb, Wf_l1, Wf_r1, b1, p, q, N);
    agg_relu_kernel<<<(N + 3) / 4, 256, 0, stream>>>(p, q, ssrc, row_start, deg, inv_deg, hb, N);

    // layer 2 (aggregate in 64-wide projected space: half the gather bytes)
    proj_kernel<64><<<(N + 63) / 64, 256, 0, stream>>>(hb, Wf_l2, Wf_r2, b2, u, v, N);
    agg_lsm_kernel<<<(N + 3) / 4, 256, 0, stream>>>(u, v, ssrc, row_start, deg, inv_deg,
                                                    (float*)d_out, N);
}

// Round 3
// 353.078 us; speedup vs baseline: 2.8263x; 1.4508x over previous
//
#include <hip/hip_runtime.h>
#include <hip/hip_bf16.h>

// GraphSAGE 2-layer, N=100K, E=1.6M, 128->128(relu)->64, log_softmax. fp32 in/out.
//
//   p = bf16(x@Wl1); q = bf16(x@Wr1 + b1)     (MFMA proj, fp32 x read directly)
//   h = bf16(relu(mean_nbr(p) + q))            (gather p, fused epilogue)
//   u = bf16(h@Wl2); v = bf16(h@Wr2 + b2)      (MFMA proj)
//   out = log_softmax(mean_nbr(u) + v)         (gather u, fused epilogue)
//
// CSR build = LDS multi-split counting sort (round-2 fill_kernel had 16x write
// amplification: random 4B scatters -> 105MB writebacks). Buckets of 512 nodes;
// ordered row_start so each bucket's ssrc window is ~32KB and L1/L2-resident.

typedef __attribute__((ext_vector_type(8))) short short8;   // 8 x bf16 = 4 VGPRs
typedef __attribute__((ext_vector_type(4))) float f32x4;

#define NPB 512          // nodes per bucket (dst >> 9)
#define BCAP 16384       // edge capacity per bucket (mean 8163, std ~90: 90-sigma margin)
#define CHUNK 8192       // edges per bucket_scatter block

__device__ __forceinline__ ushort f2bf(float f) {           // round-to-nearest-even
    unsigned u = __float_as_uint(f);
    return (ushort)((u + 0x7fff + ((u >> 16) & 1)) >> 16);
}
__device__ __forceinline__ float bflo(unsigned v) { return __uint_as_float(v << 16); }
__device__ __forceinline__ float bfhi(unsigned v) { return __uint_as_float(v & 0xffff0000u); }

// ---------- phase A: multi-split edges into node-range buckets ---------------------
// Packed entry: (src << 9) | (dst & 511)  -- src<2^17, fits 26 bits.
__global__ void bucket_scatter(const int* __restrict__ src, const int* __restrict__ dst,
                               int* __restrict__ bcount, unsigned* __restrict__ bbuf,
                               int E, int NB) {
    __shared__ int lhist[256], lbase[256], lcur[256];
    int tid = threadIdx.x;
    lhist[tid] = 0;
    __syncthreads();
    int e0 = blockIdx.x * CHUNK;
    int e1 = min(e0 + CHUNK, E);
    for (int e = e0 + tid; e < e1; e += 256)
        atomicAdd(&lhist[dst[e] >> 9], 1);
    __syncthreads();
    int h = lhist[tid];
    lbase[tid] = (h > 0) ? atomicAdd(&bcount[tid], h) : 0;   // tid>=NB has h==0
    lcur[tid] = 0;
    __syncthreads();
    for (int e = e0 + tid; e < e1; e += 256) {
        int d = dst[e], s = src[e];
        int b = d >> 9;
        int o = atomicAdd(&lcur[b], 1);
        bbuf[(long)b * BCAP + lbase[b] + o] = ((unsigned)s << 9) | (unsigned)(d & 511);
    }
}

// ---------- phase B: exclusive scan of bucket counts (NB <= 256) -------------------
__global__ void scan_buckets(const int* __restrict__ bcount, int* __restrict__ bbase, int NB) {
    __shared__ int s[256];
    int tid = threadIdx.x;
    int v = (tid < NB) ? bcount[tid] : 0;
    s[tid] = v;
    __syncthreads();
    for (int off = 1; off < 256; off <<= 1) {
        int a = (tid >= off) ? s[tid - off] : 0;
        __syncthreads();
        s[tid] += a;
        __syncthreads();
    }
    if (tid < NB) bbase[tid] = s[tid] - v;
}

// ---------- phase C: per-bucket degree count + scan + ordered placement ------------
// One block per bucket. All random writes confined to a ~32KB ssrc window.
__global__ void build_csr(const unsigned* __restrict__ bbuf, const int* __restrict__ bcount,
                          const int* __restrict__ bbase, int* __restrict__ row_start,
                          int* __restrict__ degw, float* __restrict__ inv_deg,
                          int* __restrict__ ssrc, int N) {
    __shared__ int sdeg[NPB], lcur[NPB];
    int b = blockIdx.x, tid = threadIdx.x;
    int node0 = b * NPB;
    sdeg[tid] = 0; sdeg[tid + 256] = 0;
    __syncthreads();
    int cnt = bcount[b];
    long base = (long)b * BCAP;
    for (int i = tid; i < cnt; i += 256)
        atomicAdd(&sdeg[bbuf[base + i] & 511], 1);
    __syncthreads();
    int c0 = sdeg[tid], c1 = sdeg[tid + 256];
    // inclusive Hillis-Steele scan over 512 entries
    for (int off = 1; off < NPB; off <<= 1) {
        int a0 = (tid >= off) ? sdeg[tid - off] : 0;
        int a1 = (tid + 256 >= off) ? sdeg[tid + 256 - off] : 0;
        __syncthreads();
        sdeg[tid] += a0; sdeg[tid + 256] += a1;
        __syncthreads();
    }
    int bb = bbase[b];
    int rs0 = bb + sdeg[tid] - c0;
    int rs1 = bb + sdeg[tid + 256] - c1;
    lcur[tid] = rs0; lcur[tid + 256] = rs1;
    if (node0 + tid < N) {
        row_start[node0 + tid] = rs0;
        degw[node0 + tid] = c0;
        inv_deg[node0 + tid] = 1.0f / (float)(c0 > 1 ? c0 : 1);
    }
    if (node0 + tid + 256 < N) {
        row_start[node0 + tid + 256] = rs1;
        degw[node0 + tid + 256] = c1;
        inv_deg[node0 + tid + 256] = 1.0f / (float)(c1 > 1 ? c1 : 1);
    }
    __syncthreads();
    for (int i = tid; i < cnt; i += 256) {
        unsigned w = bbuf[base + i];
        int pos = atomicAdd(&lcur[w & 511], 1);
        ssrc[pos] = (int)(w >> 9);
    }
}

// ---------- weight repack into MFMA B-fragment order -------------------------------
// idx = ((ct*16 + kc)*16 + m)*8 + j holds W[k=kc*8+j][c=ct*16+m]
__device__ __forceinline__ void wfrag_one(const float* W, ushort* Wf, int i, int COLS) {
    int j = i & 7, m = (i >> 3) & 15, kc = (i >> 7) & 15, ct = i >> 11;
    Wf[i] = f2bf(W[(kc * 8 + j) * COLS + ct * 16 + m]);
}
__global__ void cvt_w_kernel(const float* __restrict__ Wl1, const float* __restrict__ Wr1,
                             const float* __restrict__ Wl2, const float* __restrict__ Wr2,
                             ushort* __restrict__ Wf_l1, ushort* __restrict__ Wf_r1,
                             ushort* __restrict__ Wf_l2, ushort* __restrict__ Wf_r2) {
    int i = blockIdx.x * blockDim.x + threadIdx.x;   // 49152 total
    if (i < 16384)       wfrag_one(Wl1, Wf_l1, i, 128);
    else if (i < 32768)  wfrag_one(Wr1, Wf_r1, i - 16384, 128);
    else if (i < 40960)  wfrag_one(Wl2, Wf_l2, i - 32768, 64);
    else if (i < 49152)  wfrag_one(Wr2, Wf_r2, i - 40960, 64);
}

// ---------- dual projection: p = bf16(X@Wl), q = bf16(X@Wr + b) --------------------
// Block = 4 waves; wave owns a 16-row stripe, all COLS cols, K=128.
// A-frag: A[m=lane&15][k=quad*8+j]; B-frag from frag-order layout (16B coalesced).
// C/D: col = lane&15, row = quad*4 + reg.
template <int COLS, bool F32IN>
__global__ void proj_kernel(const void* __restrict__ xin,       // N x 128 (f32 or bf16)
                            const ushort* __restrict__ Wfl, const ushort* __restrict__ Wfr,
                            const float* __restrict__ bias,
                            ushort* __restrict__ p, ushort* __restrict__ q, int N) {
    constexpr int CT = COLS / 16;
    int wave = threadIdx.x >> 6, lane = threadIdx.x & 63;
    int quad = lane >> 4, m = lane & 15;
    long row0 = (long)blockIdx.x * 64 + wave * 16;
    long arow = row0 + m;
    if (arow >= N) arow = N - 1;                    // clamped load; store guarded

    f32x4 accp[CT], accq[CT];
#pragma unroll
    for (int ct = 0; ct < CT; ++ct) { accp[ct] = (f32x4)0.0f; accq[ct] = (f32x4)0.0f; }

#pragma unroll
    for (int kk = 0; kk < 128; kk += 32) {
        short8 a;
        if (F32IN) {
            const float* xf = (const float*)xin + arow * 128 + kk + quad * 8;
            float4 f0 = *(const float4*)xf;
            float4 f1 = *(const float4*)(xf + 4);
            a[0] = (short)f2bf(f0.x); a[1] = (short)f2bf(f0.y);
            a[2] = (short)f2bf(f0.z); a[3] = (short)f2bf(f0.w);
            a[4] = (short)f2bf(f1.x); a[5] = (short)f2bf(f1.y);
            a[6] = (short)f2bf(f1.z); a[7] = (short)f2bf(f1.w);
        } else {
            a = *(const short8*)((const ushort*)xin + arow * 128 + kk + quad * 8);
        }
        int kc = (kk >> 3) + quad;
#pragma unroll
        for (int ct = 0; ct < CT; ++ct) {
            long boff = (((long)(ct * 16 + kc) * 16) + m) * 8;
            short8 bl = *(const short8*)(Wfl + boff);
            short8 br = *(const short8*)(Wfr + boff);
            accp[ct] = __builtin_amdgcn_mfma_f32_16x16x32_bf16(a, bl, accp[ct], 0, 0, 0);
            accq[ct] = __builtin_amdgcn_mfma_f32_16x16x32_bf16(a, br, accq[ct], 0, 0, 0);
        }
    }

#pragma unroll
    for (int ct = 0; ct < CT; ++ct) {
        int col = ct * 16 + m;
        float bv = bias[col];
#pragma unroll
        for (int r = 0; r < 4; ++r) {
            long row = row0 + quad * 4 + r;
            if (row < N) {
                p[row * COLS + col] = f2bf(accp[ct][r]);
                q[row * COLS + col] = f2bf(accq[ct][r] + bv);
            }
        }
    }
}

// ---------- layer-1 aggregate: h = bf16(relu(mean_nbr(p) + q)) ---------------------
__global__ void agg_relu_kernel(const ushort* __restrict__ p,    // N x 128 bf16
                                const ushort* __restrict__ q,    // N x 128 bf16
                                const int* __restrict__ ssrc,
                                const int* __restrict__ row_start,
                                const int* __restrict__ deg,
                                const float* __restrict__ inv_deg,
                                ushort* __restrict__ hb, int N) {
    int wave = threadIdx.x >> 6, lane = threadIdx.x & 63;
    int n = blockIdx.x * 4 + wave;
    if (n >= N) return;
    int start = row_start[n], d = deg[n];
    const int* sp = ssrc + start;
    float ax = 0.f, ay = 0.f;
    int j = 0;
    for (; j + 4 <= d; j += 4) {       // 4 independent gathers in flight
        int s0 = sp[j], s1 = sp[j + 1], s2 = sp[j + 2], s3 = sp[j + 3];
        unsigned v0 = ((const unsigned*)(p + (long)s0 * 128))[lane];
        unsigned v1 = ((const unsigned*)(p + (long)s1 * 128))[lane];
        unsigned v2 = ((const unsigned*)(p + (long)s2 * 128))[lane];
        unsigned v3 = ((const unsigned*)(p + (long)s3 * 128))[lane];
        ax += (bflo(v0) + bflo(v1)) + (bflo(v2) + bflo(v3));
        ay += (bfhi(v0) + bfhi(v1)) + (bfhi(v2) + bfhi(v3));
    }
    for (; j < d; ++j) {
        unsigned v = ((const unsigned*)(p + (long)sp[j] * 128))[lane];
        ax += bflo(v); ay += bfhi(v);
    }
    float iv = inv_deg[n];
    unsigned qv = ((const unsigned*)(q + (long)n * 128))[lane];
    float hx = fmaxf(ax * iv + bflo(qv), 0.f);
    float hy = fmaxf(ay * iv + bfhi(qv), 0.f);
    ((unsigned*)(hb + (long)n * 128))[lane] = (unsigned)f2bf(hx) | ((unsigned)f2bf(hy) << 16);
}

// ---------- layer-2 aggregate + log_softmax ----------------------------------------
__global__ void agg_lsm_kernel(const ushort* __restrict__ u,     // N x 64 bf16
                               const ushort* __restrict__ v,     // N x 64 bf16
                               const int* __restrict__ ssrc,
                               const int* __restrict__ row_start,
                               const int* __restrict__ deg,
                               const float* __restrict__ inv_deg,
                               float* __restrict__ out, int N) {
    int wave = threadIdx.x >> 6, lane = threadIdx.x & 63;
    int n = blockIdx.x * 4 + wave;
    if (n >= N) return;
    int start = row_start[n], d = deg[n];
    const int* sp = ssrc + start;
    float a = 0.f;
    int j = 0;
    for (; j + 4 <= d; j += 4) {
        int s0 = sp[j], s1 = sp[j + 1], s2 = sp[j + 2], s3 = sp[j + 3];
        float f0 = bflo((unsigned)u[(long)s0 * 64 + lane]);
        float f1 = bflo((unsigned)u[(long)s1 * 64 + lane]);
        float f2 = bflo((unsigned)u[(long)s2 * 64 + lane]);
        float f3 = bflo((unsigned)u[(long)s3 * 64 + lane]);
        a += (f0 + f1) + (f2 + f3);
    }
    for (; j < d; ++j) a += bflo((unsigned)u[(long)sp[j] * 64 + lane]);

    float z = a * inv_deg[n] + bflo((unsigned)v[(long)n * 64 + lane]);
    float mx = z;
#pragma unroll
    for (int o = 32; o > 0; o >>= 1) mx = fmaxf(mx, __shfl_xor(mx, o));
    float e = __expf(z - mx);
    float s = e;
#pragma unroll
    for (int o = 32; o > 0; o >>= 1) s += __shfl_xor(s, o);
    out[(long)n * 64 + lane] = z - mx - __logf(s);
}

// -----------------------------------------------------------------------------------
extern "C" void kernel_launch(void* const* d_in, const int* in_sizes, int n_in,
                              void* d_out, int out_size, void* d_ws, size_t ws_size,
                              hipStream_t stream) {
    const float* x   = (const float*)d_in[0];
    const int*   ei  = (const int*)d_in[1];
    const float* Wl1 = (const float*)d_in[2];
    const float* Wr1 = (const float*)d_in[3];
    const float* b1  = (const float*)d_in[4];
    const float* Wl2 = (const float*)d_in[5];
    const float* Wr2 = (const float*)d_in[6];
    const float* b2  = (const float*)d_in[7];

    const int N = in_sizes[0] / 128;
    const int E = in_sizes[1] / 2;
    const int* src = ei;
    const int* dst = ei + E;
    const int NB = (N + NPB - 1) / NPB;             // 196 buckets (<= 256 for N <= 131072)

    size_t off = 0;
    auto take = [&](size_t nbytes) -> void* {
        void* ptr = (void*)((char*)d_ws + off);
        off += (nbytes + 255) & ~(size_t)255;
        return ptr;
    };
    int*      bcount    = (int*)take((size_t)NB * 4);
    int*      bbase     = (int*)take((size_t)NB * 4);
    unsigned* bbuf      = (unsigned*)take((size_t)NB * BCAP * 4);   // 12.8 MB
    int*      row_start = (int*)take((size_t)N * 4);
    int*      degw      = (int*)take((size_t)N * 4);
    float*    inv_deg   = (float*)take((size_t)N * 4);
    int*      ssrc      = (int*)take((size_t)E * 4);
    ushort*   p         = (ushort*)take((size_t)N * 128 * 2);       // reused as u
    ushort*   q         = (ushort*)take((size_t)N * 128 * 2);       // reused as v
    ushort*   hb        = (ushort*)take((size_t)N * 128 * 2);
    ushort*   Wf_l1     = (ushort*)take(128 * 128 * 2);
    ushort*   Wf_r1     = (ushort*)take(128 * 128 * 2);
    ushort*   Wf_l2     = (ushort*)take(64 * 128 * 2);
    ushort*   Wf_r2     = (ushort*)take(64 * 128 * 2);
    ushort*   u = p;    // p dead after agg_relu
    ushort*   v = q;    // q dead after agg_relu
    (void)ws_size; (void)n_in; (void)out_size;

    hipMemsetAsync(bcount, 0, (size_t)NB * 4, stream);

    bucket_scatter<<<(E + CHUNK - 1) / CHUNK, 256, 0, stream>>>(src, dst, bcount, bbuf, E, NB);
    scan_buckets  <<<1, 256, 0, stream>>>(bcount, bbase, NB);
    build_csr     <<<NB, 256, 0, stream>>>(bbuf, bcount, bbase, row_start, degw, inv_deg, ssrc, N);
    cvt_w_kernel  <<<192, 256, 0, stream>>>(Wl1, Wr1, Wl2, Wr2, Wf_l1, Wf_r1, Wf_l2, Wf_r2);

    // layer 1
    proj_kernel<128, true><<<(N + 63) / 64, 256, 0, stream>>>(x, Wf_l1, Wf_r1, b1, p, q, N);
    agg_relu_kernel<<<(N + 3) / 4, 256, 0, stream>>>(p, q, ssrc, row_start, degw, inv_deg, hb, N);

    // layer 2 (aggregate in 64-wide projected space)
    proj_kernel<64, false><<<(N + 63) / 64, 256, 0, stream>>>(hb, Wf_l2, Wf_r2, b2, u, v, N);
    agg_lsm_kernel<<<(N + 3) / 4, 256, 0, stream>>>(u, v, ssrc, row_start, degw, inv_deg,
                                                    (float*)d_out, N);
}

// Round 4
// 314.014 us; speedup vs baseline: 3.1779x; 1.1244x over previous
//
#include <hip/hip_runtime.h>
#include <hip/hip_bf16.h>

// GraphSAGE 2-layer, N=100K, E=1.6M, 128->128(relu)->64, log_softmax. fp32 in/out.
//
//   p = fp8(x@Wl1); q = bf16(x@Wr1 + b1)      (MFMA proj, operand-swapped)
//   h = bf16(relu(mean_nbr(p) + q))            (gather p fp8: 2 rows/instr)
//   u = fp8(h@Wl2); v = bf16(h@Wr2 + b2)       (MFMA proj)
//   out = log_softmax(mean_nbr(u) + v)         (gather u fp8: 4 rows/instr)
//
// fp8 (OCP e4m3 via v_cvt_pk_*_fp8) halves gather bytes vs bf16; error budget OK:
// per-elem rms ~3.6% rel on sigma~0.6 values, averaged over deg~16, gain<1 into out.
// CSR build = LDS multi-split counting sort (r2's random 4B scatters had 16x write
// amplification). Ordered row_start => each bucket's ssrc window is L1/L2-resident.

typedef __attribute__((ext_vector_type(8))) short short8;   // 8 x bf16 = 4 VGPRs
typedef __attribute__((ext_vector_type(4))) float f32x4;
typedef __attribute__((ext_vector_type(2))) float f32x2;

#define NPB 512          // nodes per bucket (dst >> 9)
#define BCAP 16384       // edge capacity per bucket (mean 8163)
#define CHUNK 8192       // edges per bucket_scatter block

__device__ __forceinline__ ushort f2bf(float f) {           // round-to-nearest-even
    unsigned u = __float_as_uint(f);
    return (ushort)((u + 0x7fff + ((u >> 16) & 1)) >> 16);
}
__device__ __forceinline__ float bflo(unsigned v) { return __uint_as_float(v << 16); }
__device__ __forceinline__ float bfhi(unsigned v) { return __uint_as_float(v & 0xffff0000u); }
__device__ __forceinline__ unsigned pk4bf(float a, float b) {
    return (unsigned)f2bf(a) | ((unsigned)f2bf(b) << 16);
}

// ---------- phase A: multi-split edges into node-range buckets ---------------------
__global__ void bucket_scatter(const int* __restrict__ src, const int* __restrict__ dst,
                               int* __restrict__ bcount, unsigned* __restrict__ bbuf,
                               int E, int NB) {
    __shared__ int lhist[256], lbase[256], lcur[256];
    int tid = threadIdx.x;
    lhist[tid] = 0;
    __syncthreads();
    int e0 = blockIdx.x * CHUNK;
    int e1 = min(e0 + CHUNK, E);
    for (int e = e0 + tid; e < e1; e += 256)
        atomicAdd(&lhist[dst[e] >> 9], 1);
    __syncthreads();
    int h = lhist[tid];
    lbase[tid] = (h > 0) ? atomicAdd(&bcount[tid], h) : 0;
    lcur[tid] = 0;
    __syncthreads();
    for (int e = e0 + tid; e < e1; e += 256) {
        int d = dst[e], s = src[e];
        int b = d >> 9;
        int o = atomicAdd(&lcur[b], 1);
        bbuf[(long)b * BCAP + lbase[b] + o] = ((unsigned)s << 9) | (unsigned)(d & 511);
    }
}

// ---------- phase B: exclusive scan of bucket counts (NB <= 256) -------------------
__global__ void scan_buckets(const int* __restrict__ bcount, int* __restrict__ bbase, int NB) {
    __shared__ int s[256];
    int tid = threadIdx.x;
    int v = (tid < NB) ? bcount[tid] : 0;
    s[tid] = v;
    __syncthreads();
    for (int off = 1; off < 256; off <<= 1) {
        int a = (tid >= off) ? s[tid - off] : 0;
        __syncthreads();
        s[tid] += a;
        __syncthreads();
    }
    if (tid < NB) bbase[tid] = s[tid] - v;
}

// ---------- phase C: per-bucket degree count + scan + ordered placement ------------
__global__ void build_csr(const unsigned* __restrict__ bbuf, const int* __restrict__ bcount,
                          const int* __restrict__ bbase, int* __restrict__ row_start,
                          int* __restrict__ degw, float* __restrict__ inv_deg,
                          int* __restrict__ ssrc, int N) {
    __shared__ int sdeg[NPB], lcur[NPB];
    int b = blockIdx.x, tid = threadIdx.x;
    int node0 = b * NPB;
    sdeg[tid] = 0; sdeg[tid + 256] = 0;
    __syncthreads();
    int cnt = bcount[b];
    long base = (long)b * BCAP;
    for (int i = tid; i < cnt; i += 256)
        atomicAdd(&sdeg[bbuf[base + i] & 511], 1);
    __syncthreads();
    int c0 = sdeg[tid], c1 = sdeg[tid + 256];
    for (int off = 1; off < NPB; off <<= 1) {   // inclusive Hillis-Steele over 512
        int a0 = (tid >= off) ? sdeg[tid - off] : 0;
        int a1 = (tid + 256 >= off) ? sdeg[tid + 256 - off] : 0;
        __syncthreads();
        sdeg[tid] += a0; sdeg[tid + 256] += a1;
        __syncthreads();
    }
    int bb = bbase[b];
    int rs0 = bb + sdeg[tid] - c0;
    int rs1 = bb + sdeg[tid + 256] - c1;
    lcur[tid] = rs0; lcur[tid + 256] = rs1;
    if (node0 + tid < N) {
        row_start[node0 + tid] = rs0;
        degw[node0 + tid] = c0;
        inv_deg[node0 + tid] = 1.0f / (float)(c0 > 1 ? c0 : 1);
    }
    if (node0 + tid + 256 < N) {
        row_start[node0 + tid + 256] = rs1;
        degw[node0 + tid + 256] = c1;
        inv_deg[node0 + tid + 256] = 1.0f / (float)(c1 > 1 ? c1 : 1);
    }
    __syncthreads();
    for (int i = tid; i < cnt; i += 256) {
        unsigned w = bbuf[base + i];
        int pos = atomicAdd(&lcur[w & 511], 1);
        ssrc[pos] = (int)(w >> 9);
    }
}

// ---------- weight repack into MFMA fragment order ---------------------------------
// idx = ((ct*16 + kc)*16 + m)*8 + j holds W[k=kc*8+j][c=ct*16+m]; used as A-operand:
// A[m=lane&15 -> weight col][k=quad*8+j].
__device__ __forceinline__ void wfrag_one(const float* W, ushort* Wf, int i, int COLS) {
    int j = i & 7, m = (i >> 3) & 15, kc = (i >> 7) & 15, ct = i >> 11;
    Wf[i] = f2bf(W[(kc * 8 + j) * COLS + ct * 16 + m]);
}
__global__ void cvt_w_kernel(const float* __restrict__ Wl1, const float* __restrict__ Wr1,
                             const float* __restrict__ Wl2, const float* __restrict__ Wr2,
                             ushort* __restrict__ Wf_l1, ushort* __restrict__ Wf_r1,
                             ushort* __restrict__ Wf_l2, ushort* __restrict__ Wf_r2) {
    int i = blockIdx.x * blockDim.x + threadIdx.x;   // 49152 total
    if (i < 16384)       wfrag_one(Wl1, Wf_l1, i, 128);
    else if (i < 32768)  wfrag_one(Wr1, Wf_r1, i - 16384, 128);
    else if (i < 40960)  wfrag_one(Wl2, Wf_l2, i - 32768, 64);
    else if (i < 49152)  wfrag_one(Wr2, Wf_r2, i - 40960, 64);
}

// ---------- dual projection: p = fp8(X@Wl), q = bf16(X@Wr + b) ---------------------
// Operand-swapped MFMA: D = Wfrag(A) * Xfrag(B)  =>  D col (lane&15) = node,
// D row (quad*4+reg) = weight col. Lane thus holds 4 CONSECUTIVE output cols of one
// node per (ct) => p packs to one dword (4xfp8), q to one 8B (4xbf16) store.
template <int COLS, bool F32IN>
__global__ void proj_kernel(const void* __restrict__ xin,       // N x 128 (f32 or bf16)
                            const ushort* __restrict__ Wfl, const ushort* __restrict__ Wfr,
                            const float* __restrict__ bias,
                            unsigned char* __restrict__ p8,     // N x COLS fp8
                            ushort* __restrict__ q,             // N x COLS bf16
                            int N) {
    constexpr int CT = COLS / 16;
    int wave = threadIdx.x >> 6, lane = threadIdx.x & 63;
    int quad = lane >> 4, m = lane & 15;
    long row0 = (long)blockIdx.x * 64 + wave * 16;
    long node = row0 + m;                   // lane&15 = node (D col dim)
    long arow = (node < N) ? node : (N - 1);

    f32x4 accp[CT], accq[CT];
#pragma unroll
    for (int ct = 0; ct < CT; ++ct) { accp[ct] = (f32x4)0.0f; accq[ct] = (f32x4)0.0f; }

#pragma unroll
    for (int kk = 0; kk < 128; kk += 32) {
        short8 b;                            // B-frag: B[k][n=lane&15] = x[node][k]
        if (F32IN) {
            const float* xf = (const float*)xin + arow * 128 + kk + quad * 8;
            float4 f0 = *(const float4*)xf;
            float4 f1 = *(const float4*)(xf + 4);
            b[0] = (short)f2bf(f0.x); b[1] = (short)f2bf(f0.y);
            b[2] = (short)f2bf(f0.z); b[3] = (short)f2bf(f0.w);
            b[4] = (short)f2bf(f1.x); b[5] = (short)f2bf(f1.y);
            b[6] = (short)f2bf(f1.z); b[7] = (short)f2bf(f1.w);
        } else {
            b = *(const short8*)((const ushort*)xin + arow * 128 + kk + quad * 8);
        }
        int kc = (kk >> 3) + quad;
#pragma unroll
        for (int ct = 0; ct < CT; ++ct) {
            long boff = (((long)(ct * 16 + kc) * 16) + m) * 8;
            short8 al = *(const short8*)(Wfl + boff);   // A-frag (weights)
            short8 ar = *(const short8*)(Wfr + boff);
            accp[ct] = __builtin_amdgcn_mfma_f32_16x16x32_bf16(al, b, accp[ct], 0, 0, 0);
            accq[ct] = __builtin_amdgcn_mfma_f32_16x16x32_bf16(ar, b, accq[ct], 0, 0, 0);
        }
    }

    if (node < N) {
#pragma unroll
        for (int ct = 0; ct < CT; ++ct) {
            int c0 = ct * 16 + quad * 4;            // 4 consecutive cols per lane
            float4 bv = *(const float4*)(bias + c0);
            float q0 = accq[ct][0] + bv.x, q1 = accq[ct][1] + bv.y;
            float q2 = accq[ct][2] + bv.z, q3 = accq[ct][3] + bv.w;
            unsigned w = (unsigned)__builtin_amdgcn_cvt_pk_fp8_f32(accp[ct][0], accp[ct][1], 0, false);
            w = (unsigned)__builtin_amdgcn_cvt_pk_fp8_f32(accp[ct][2], accp[ct][3], (int)w, true);
            *(unsigned*)(p8 + node * COLS + c0) = w;
            uint2 qw; qw.x = pk4bf(q0, q1); qw.y = pk4bf(q2, q3);
            *(uint2*)(q + node * COLS + c0) = qw;
        }
    }
}

// ---------- layer-1 aggregate: h = bf16(relu(mean_nbr(p) + q)) ---------------------
// fp8 rows are 128B: lanes 0-31 gather row A, 32-63 row B => 2 edges per instruction.
__global__ void agg_relu_kernel(const unsigned char* __restrict__ p8,  // N x 128 fp8
                                const ushort* __restrict__ q,          // N x 128 bf16
                                const int* __restrict__ ssrc,
                                const int* __restrict__ row_start,
                                const int* __restrict__ deg,
                                const float* __restrict__ inv_deg,
                                ushort* __restrict__ hb, int N) {
    int wave = threadIdx.x >> 6, lane = threadIdx.x & 63;
    int n = blockIdx.x * 4 + wave;
    if (n >= N) return;
    int half = lane >> 5, lm = lane & 31;          // cols 4*lm .. 4*lm+3
    int start = row_start[n], d = deg[n];
    const int* sp = ssrc + start;
    const unsigned char* pb = p8 + lm * 4;
    float a0 = 0.f, a1 = 0.f, a2 = 0.f, a3 = 0.f;
    int j = 0;
    for (; j + 8 <= d; j += 8) {                   // 4 loads = 8 edges in flight
        int s0 = sp[j + half], s1 = sp[j + 2 + half];
        int s2 = sp[j + 4 + half], s3 = sp[j + 6 + half];
        unsigned v0 = *(const unsigned*)(pb + (long)s0 * 128);
        unsigned v1 = *(const unsigned*)(pb + (long)s1 * 128);
        unsigned v2 = *(const unsigned*)(pb + (long)s2 * 128);
        unsigned v3 = *(const unsigned*)(pb + (long)s3 * 128);
        f32x2 l0 = __builtin_amdgcn_cvt_pk_f32_fp8((int)v0, false);
        f32x2 h0 = __builtin_amdgcn_cvt_pk_f32_fp8((int)v0, true);
        f32x2 l1 = __builtin_amdgcn_cvt_pk_f32_fp8((int)v1, false);
        f32x2 h1 = __builtin_amdgcn_cvt_pk_f32_fp8((int)v1, true);
        f32x2 l2 = __builtin_amdgcn_cvt_pk_f32_fp8((int)v2, false);
        f32x2 h2 = __builtin_amdgcn_cvt_pk_f32_fp8((int)v2, true);
        f32x2 l3 = __builtin_amdgcn_cvt_pk_f32_fp8((int)v3, false);
        f32x2 h3 = __builtin_amdgcn_cvt_pk_f32_fp8((int)v3, true);
        a0 += (l0[0] + l1[0]) + (l2[0] + l3[0]);
        a1 += (l0[1] + l1[1]) + (l2[1] + l3[1]);
        a2 += (h0[0] + h1[0]) + (h2[0] + h3[0]);
        a3 += (h0[1] + h1[1]) + (h2[1] + h3[1]);
    }
    for (; j < d; j += 2) {                        // predicated tail, 2 edges/iter
        int idx = j + half;
        int s = sp[idx < d ? idx : j];
        unsigned v = *(const unsigned*)(pb + (long)s * 128);
        if (idx < d) {
            f32x2 lo = __builtin_amdgcn_cvt_pk_f32_fp8((int)v, false);
            f32x2 hi = __builtin_amdgcn_cvt_pk_f32_fp8((int)v, true);
            a0 += lo[0]; a1 += lo[1]; a2 += hi[0]; a3 += hi[1];
        }
    }
    a0 += __shfl_xor(a0, 32); a1 += __shfl_xor(a1, 32);
    a2 += __shfl_xor(a2, 32); a3 += __shfl_xor(a3, 32);
    if (half == 0) {
        float iv = inv_deg[n];
        uint2 qv = *(const uint2*)(q + (long)n * 128 + lm * 4);
        float h0 = fmaxf(a0 * iv + bflo(qv.x), 0.f);
        float h1 = fmaxf(a1 * iv + bfhi(qv.x), 0.f);
        float h2 = fmaxf(a2 * iv + bflo(qv.y), 0.f);
        float h3 = fmaxf(a3 * iv + bfhi(qv.y), 0.f);
        uint2 hw; hw.x = pk4bf(h0, h1); hw.y = pk4bf(h2, h3);
        *(uint2*)(hb + (long)n * 128 + lm * 4) = hw;
    }
}

// ---------- layer-2 aggregate + log_softmax ----------------------------------------
// fp8 rows are 64B: 4 rows per wave instruction (16 lanes each).
__global__ void agg_lsm_kernel(const unsigned char* __restrict__ u8,   // N x 64 fp8
                               const ushort* __restrict__ v,           // N x 64 bf16
                               const int* __restrict__ ssrc,
                               const int* __restrict__ row_start,
                               const int* __restrict__ deg,
                               const float* __restrict__ inv_deg,
                               float* __restrict__ out, int N) {
    int wave = threadIdx.x >> 6, lane = threadIdx.x & 63;
    int n = blockIdx.x * 4 + wave;
    if (n >= N) return;
    int qtr = lane >> 4, lm = lane & 15;           // cols 4*lm .. 4*lm+3
    int start = row_start[n], d = deg[n];
    const int* sp = ssrc + start;
    const unsigned char* ub = u8 + lm * 4;
    float a0 = 0.f, a1 = 0.f, a2 = 0.f, a3 = 0.f;
    int j = 0;
    for (; j + 16 <= d; j += 16) {                 // 4 loads = 16 edges in flight
        int s0 = sp[j + qtr], s1 = sp[j + 4 + qtr];
        int s2 = sp[j + 8 + qtr], s3 = sp[j + 12 + qtr];
        unsigned v0 = *(const unsigned*)(ub + (long)s0 * 64);
        unsigned v1 = *(const unsigned*)(ub + (long)s1 * 64);
        unsigned v2 = *(const unsigned*)(ub + (long)s2 * 64);
        unsigned v3 = *(const unsigned*)(ub + (long)s3 * 64);
        f32x2 l0 = __builtin_amdgcn_cvt_pk_f32_fp8((int)v0, false);
        f32x2 h0 = __builtin_amdgcn_cvt_pk_f32_fp8((int)v0, true);
        f32x2 l1 = __builtin_amdgcn_cvt_pk_f32_fp8((int)v1, false);
        f32x2 h1 = __builtin_amdgcn_cvt_pk_f32_fp8((int)v1, true);
        f32x2 l2 = __builtin_amdgcn_cvt_pk_f32_fp8((int)v2, false);
        f32x2 h2 = __builtin_amdgcn_cvt_pk_f32_fp8((int)v2, true);
        f32x2 l3 = __builtin_amdgcn_cvt_pk_f32_fp8((int)v3, false);
        f32x2 h3 = __builtin_amdgcn_cvt_pk_f32_fp8((int)v3, true);
        a0 += (l0[0] + l1[0]) + (l2[0] + l3[0]);
        a1 += (l0[1] + l1[1]) + (l2[1] + l3[1]);
        a2 += (h0[0] + h1[0]) + (h2[0] + h3[0]);
        a3 += (h0[1] + h1[1]) + (h2[1] + h3[1]);
    }
    for (; j < d; j += 4) {                        // predicated tail, 4 edges/iter
        int idx = j + qtr;
        int s = sp[idx < d ? idx : j];
        unsigned vv = *(const unsigned*)(ub + (long)s * 64);
        if (idx < d) {
            f32x2 lo = __builtin_amdgcn_cvt_pk_f32_fp8((int)vv, false);
            f32x2 hi = __builtin_amdgcn_cvt_pk_f32_fp8((int)vv, true);
            a0 += lo[0]; a1 += lo[1]; a2 += hi[0]; a3 += hi[1];
        }
    }
    a0 += __shfl_xor(a0, 16); a1 += __shfl_xor(a1, 16);
    a2 += __shfl_xor(a2, 16); a3 += __shfl_xor(a3, 16);
    a0 += __shfl_xor(a0, 32); a1 += __shfl_xor(a1, 32);
    a2 += __shfl_xor(a2, 32); a3 += __shfl_xor(a3, 32);

    float iv = inv_deg[n];
    uint2 vv = *(const uint2*)(v + (long)n * 64 + lm * 4);
    float z0 = a0 * iv + bflo(vv.x);
    float z1 = a1 * iv + bfhi(vv.x);
    float z2 = a2 * iv + bflo(vv.y);
    float z3 = a3 * iv + bfhi(vv.y);
    float mx = fmaxf(fmaxf(z0, z1), fmaxf(z2, z3));
#pragma unroll
    for (int o = 8; o > 0; o >>= 1) mx = fmaxf(mx, __shfl_xor(mx, o));   // over lm bits
    float e = __expf(z0 - mx) + __expf(z1 - mx) + __expf(z2 - mx) + __expf(z3 - mx);
#pragma unroll
    for (int o = 8; o > 0; o >>= 1) e += __shfl_xor(e, o);
    float ls = mx + __logf(e);
    if (qtr == 0) {
        float4 o4;
        o4.x = z0 - ls; o4.y = z1 - ls; o4.z = z2 - ls; o4.w = z3 - ls;
        *(float4*)(out + (long)n * 64 + lm * 4) = o4;
    }
}

// -----------------------------------------------------------------------------------
extern "C" void kernel_launch(void* const* d_in, const int* in_sizes, int n_in,
                              void* d_out, int out_size, void* d_ws, size_t ws_size,
                              hipStream_t stream) {
    const float* x   = (const float*)d_in[0];
    const int*   ei  = (const int*)d_in[1];
    const float* Wl1 = (const float*)d_in[2];
    const float* Wr1 = (const float*)d_in[3];
    const float* b1  = (const float*)d_in[4];
    const float* Wl2 = (const float*)d_in[5];
    const float* Wr2 = (const float*)d_in[6];
    const float* b2  = (const float*)d_in[7];

    const int N = in_sizes[0] / 128;
    const int E = in_sizes[1] / 2;
    const int* src = ei;
    const int* dst = ei + E;
    const int NB = (N + NPB - 1) / NPB;

    size_t off = 0;
    auto take = [&](size_t nbytes) -> void* {
        void* ptr = (void*)((char*)d_ws + off);
        off += (nbytes + 255) & ~(size_t)255;
        return ptr;
    };
    int*      bcount    = (int*)take((size_t)NB * 4);
    int*      bbase     = (int*)take((size_t)NB * 4);
    unsigned* bbuf      = (unsigned*)take((size_t)NB * BCAP * 4);   // 12.8 MB
    int*      row_start = (int*)take((size_t)N * 4);
    int*      degw      = (int*)take((size_t)N * 4);
    float*    inv_deg   = (float*)take((size_t)N * 4);
    int*      ssrc      = (int*)take((size_t)E * 4);
    unsigned char* p8   = (unsigned char*)take((size_t)N * 128);    // reused as u8
    ushort*   q         = (ushort*)take((size_t)N * 128 * 2);       // reused as v
    ushort*   hb        = (ushort*)take((size_t)N * 128 * 2);
    ushort*   Wf_l1     = (ushort*)take(128 * 128 * 2);
    ushort*   Wf_r1     = (ushort*)take(128 * 128 * 2);
    ushort*   Wf_l2     = (ushort*)take(64 * 128 * 2);
    ushort*   Wf_r2     = (ushort*)take(64 * 128 * 2);
    unsigned char* u8 = p8;   // p dead after agg_relu
    ushort*        v  = q;    // q dead after agg_relu
    (void)ws_size; (void)n_in; (void)out_size;

    hipMemsetAsync(bcount, 0, (size_t)NB * 4, stream);

    bucket_scatter<<<(E + CHUNK - 1) / CHUNK, 256, 0, stream>>>(src, dst, bcount, bbuf, E, NB);
    scan_buckets  <<<1, 256, 0, stream>>>(bcount, bbase, NB);
    build_csr     <<<NB, 256, 0, stream>>>(bbuf, bcount, bbase, row_start, degw, inv_deg, ssrc, N);
    cvt_w_kernel  <<<192, 256, 0, stream>>>(Wl1, Wr1, Wl2, Wr2, Wf_l1, Wf_r1, Wf_l2, Wf_r2);

    // layer 1
    proj_kernel<128, true><<<(N + 63) / 64, 256, 0, stream>>>(x, Wf_l1, Wf_r1, b1, p8, q, N);
    agg_relu_kernel<<<(N + 3) / 4, 256, 0, stream>>>(p8, q, ssrc, row_start, degw, inv_deg, hb, N);

    // layer 2 (aggregate in 64-wide projected fp8 space: table ~6.4MB, near L2-resident)
    proj_kernel<64, false><<<(N + 63) / 64, 256, 0, stream>>>(hb, Wf_l2, Wf_r2, b2, u8, v, N);
    agg_lsm_kernel<<<(N + 3) / 4, 256, 0, stream>>>(u8, v, ssrc, row_start, degw, inv_deg,
                                                    (float*)d_out, N);
}

// Round 5
// 297.482 us; speedup vs baseline: 3.3545x; 1.0556x over previous
//
#include <hip/hip_runtime.h>
#include <hip/hip_bf16.h>

// GraphSAGE 2-layer, N=100K, E=1.6M, 128->128(relu)->64, log_softmax. fp32 in/out.
//
//   p = fp8(x@Wl1); q = bf16(x@Wr1 + b1)      (MFMA proj, operand-swapped)
//   h = bf16(relu(mean_nbr(p) + q))            (gather p fp8: 16 lanes/edge, 8B/lane)
//   u = fp8(h@Wl2); v = bf16(h@Wr2 + b2)       (MFMA proj)
//   out = log_softmax(mean_nbr(u) + v)         (gather u fp8: 8 lanes/edge)
//
// r4 agg_relu was latency-bound (HBM 28%, VALU 38%, occ 66%): 1 VMEM/edge, 1KB/wave
// in flight. r5: one wave-instr fetches 4 rows (512B), 4 row-loads in flight (2KB),
// column sums merged by 2 shfl_xor rounds once per node.

typedef __attribute__((ext_vector_type(8))) short short8;   // 8 x bf16 = 4 VGPRs
typedef __attribute__((ext_vector_type(4))) float f32x4;
typedef __attribute__((ext_vector_type(2))) float f32x2;

#define NPB 512          // nodes per bucket (dst >> 9)
#define BCAP 16384       // edge capacity per bucket (mean 8163)
#define CHUNK 8192       // edges per bucket_scatter block

__device__ __forceinline__ ushort f2bf(float f) {           // round-to-nearest-even
    unsigned u = __float_as_uint(f);
    return (ushort)((u + 0x7fff + ((u >> 16) & 1)) >> 16);
}
__device__ __forceinline__ float bflo(unsigned v) { return __uint_as_float(v << 16); }
__device__ __forceinline__ float bfhi(unsigned v) { return __uint_as_float(v & 0xffff0000u); }
__device__ __forceinline__ unsigned pk4bf(float a, float b) {
    return (unsigned)f2bf(a) | ((unsigned)f2bf(b) << 16);
}

// ---------- phase A: multi-split edges into node-range buckets ---------------------
// Single global read of src/dst (int4); entries staged in LDS for the scatter pass.
__global__ void bucket_scatter(const int* __restrict__ src, const int* __restrict__ dst,
                               int* __restrict__ bcount, unsigned* __restrict__ bbuf,
                               int E, int NB) {
    __shared__ unsigned entry[CHUNK];        // 32 KB: (src<<9)|(dst&511)
    __shared__ unsigned char ebkt[CHUNK];    // 8 KB: bucket id (dst>>9 < 256)
    __shared__ int lhist[256], lbase[256], lcur[256];
    int tid = threadIdx.x;
    lhist[tid] = 0;
    __syncthreads();
    int e0 = blockIdx.x * CHUNK;
    int cnt = min(CHUNK, E - e0);
    int nv = cnt >> 2;
    for (int t = tid; t < nv; t += 256) {
        int4 d4 = ((const int4*)(dst + e0))[t];
        int4 s4 = ((const int4*)(src + e0))[t];
        int i = t * 4;
        int b0 = d4.x >> 9, b1 = d4.y >> 9, b2 = d4.z >> 9, b3 = d4.w >> 9;
        entry[i + 0] = ((unsigned)s4.x << 9) | (unsigned)(d4.x & 511);
        entry[i + 1] = ((unsigned)s4.y << 9) | (unsigned)(d4.y & 511);
        entry[i + 2] = ((unsigned)s4.z << 9) | (unsigned)(d4.z & 511);
        entry[i + 3] = ((unsigned)s4.w << 9) | (unsigned)(d4.w & 511);
        ebkt[i + 0] = (unsigned char)b0; ebkt[i + 1] = (unsigned char)b1;
        ebkt[i + 2] = (unsigned char)b2; ebkt[i + 3] = (unsigned char)b3;
        atomicAdd(&lhist[b0], 1); atomicAdd(&lhist[b1], 1);
        atomicAdd(&lhist[b2], 1); atomicAdd(&lhist[b3], 1);
    }
    for (int i = (nv << 2) + tid; i < cnt; i += 256) {   // scalar remainder
        int d = dst[e0 + i], s = src[e0 + i];
        int b = d >> 9;
        entry[i] = ((unsigned)s << 9) | (unsigned)(d & 511);
        ebkt[i] = (unsigned char)b;
        atomicAdd(&lhist[b], 1);
    }
    __syncthreads();
    int h = lhist[tid];
    lbase[tid] = (h > 0) ? atomicAdd(&bcount[tid], h) : 0;
    lcur[tid] = 0;
    __syncthreads();
    for (int i = tid; i < cnt; i += 256) {
        int b = ebkt[i];
        int o = atomicAdd(&lcur[b], 1);
        bbuf[(long)b * BCAP + lbase[b] + o] = entry[i];
    }
}

// ---------- phase B: exclusive scan of bucket counts (NB <= 256) -------------------
__global__ void scan_buckets(const int* __restrict__ bcount, int* __restrict__ bbase, int NB) {
    __shared__ int s[256];
    int tid = threadIdx.x;
    int v = (tid < NB) ? bcount[tid] : 0;
    s[tid] = v;
    __syncthreads();
    for (int off = 1; off < 256; off <<= 1) {
        int a = (tid >= off) ? s[tid - off] : 0;
        __syncthreads();
        s[tid] += a;
        __syncthreads();
    }
    if (tid < NB) bbase[tid] = s[tid] - v;
}

// ---------- phase C: per-bucket degree count + scan + ordered placement ------------
__global__ void build_csr(const unsigned* __restrict__ bbuf, const int* __restrict__ bcount,
                          const int* __restrict__ bbase, int* __restrict__ row_start,
                          int* __restrict__ degw, float* __restrict__ inv_deg,
                          int* __restrict__ ssrc, int N) {
    __shared__ int sdeg[NPB], lcur[NPB];
    int b = blockIdx.x, tid = threadIdx.x;
    int node0 = b * NPB;
    sdeg[tid] = 0; sdeg[tid + 256] = 0;
    __syncthreads();
    int cnt = bcount[b];
    long base = (long)b * BCAP;
    for (int i = tid; i < cnt; i += 256)
        atomicAdd(&sdeg[bbuf[base + i] & 511], 1);
    __syncthreads();
    int c0 = sdeg[tid], c1 = sdeg[tid + 256];
    for (int off = 1; off < NPB; off <<= 1) {   // inclusive Hillis-Steele over 512
        int a0 = (tid >= off) ? sdeg[tid - off] : 0;
        int a1 = (tid + 256 >= off) ? sdeg[tid + 256 - off] : 0;
        __syncthreads();
        sdeg[tid] += a0; sdeg[tid + 256] += a1;
        __syncthreads();
    }
    int bb = bbase[b];
    int rs0 = bb + sdeg[tid] - c0;
    int rs1 = bb + sdeg[tid + 256] - c1;
    lcur[tid] = rs0; lcur[tid + 256] = rs1;
    if (node0 + tid < N) {
        row_start[node0 + tid] = rs0;
        degw[node0 + tid] = c0;
        inv_deg[node0 + tid] = 1.0f / (float)(c0 > 1 ? c0 : 1);
    }
    if (node0 + tid + 256 < N) {
        row_start[node0 + tid + 256] = rs1;
        degw[node0 + tid + 256] = c1;
        inv_deg[node0 + tid + 256] = 1.0f / (float)(c1 > 1 ? c1 : 1);
    }
    __syncthreads();
    for (int i = tid; i < cnt; i += 256) {
        unsigned w = bbuf[base + i];
        int pos = atomicAdd(&lcur[w & 511], 1);
        ssrc[pos] = (int)(w >> 9);
    }
}

// ---------- weight repack into MFMA fragment order ---------------------------------
__device__ __forceinline__ void wfrag_one(const float* W, ushort* Wf, int i, int COLS) {
    int j = i & 7, m = (i >> 3) & 15, kc = (i >> 7) & 15, ct = i >> 11;
    Wf[i] = f2bf(W[(kc * 8 + j) * COLS + ct * 16 + m]);
}
__global__ void cvt_w_kernel(const float* __restrict__ Wl1, const float* __restrict__ Wr1,
                             const float* __restrict__ Wl2, const float* __restrict__ Wr2,
                             ushort* __restrict__ Wf_l1, ushort* __restrict__ Wf_r1,
                             ushort* __restrict__ Wf_l2, ushort* __restrict__ Wf_r2) {
    int i = blockIdx.x * blockDim.x + threadIdx.x;   // 49152 total
    if (i < 16384)       wfrag_one(Wl1, Wf_l1, i, 128);
    else if (i < 32768)  wfrag_one(Wr1, Wf_r1, i - 16384, 128);
    else if (i < 40960)  wfrag_one(Wl2, Wf_l2, i - 32768, 64);
    else if (i < 49152)  wfrag_one(Wr2, Wf_r2, i - 40960, 64);
}

// ---------- dual projection: p = fp8(X@Wl), q = bf16(X@Wr + b) ---------------------
// Operand-swapped MFMA: D = Wfrag(A) * Xfrag(B) => lane holds 4 consecutive output
// cols of one node per ct => p packs to one dword (4xfp8), q to 8B (4xbf16).
template <int COLS, bool F32IN>
__global__ void proj_kernel(const void* __restrict__ xin,       // N x 128 (f32 or bf16)
                            const ushort* __restrict__ Wfl, const ushort* __restrict__ Wfr,
                            const float* __restrict__ bias,
                            unsigned char* __restrict__ p8,     // N x COLS fp8
                            ushort* __restrict__ q,             // N x COLS bf16
                            int N) {
    constexpr int CT = COLS / 16;
    int wave = threadIdx.x >> 6, lane = threadIdx.x & 63;
    int quad = lane >> 4, m = lane & 15;
    long row0 = (long)blockIdx.x * 64 + wave * 16;
    long node = row0 + m;
    long arow = (node < N) ? node : (N - 1);

    f32x4 accp[CT], accq[CT];
#pragma unroll
    for (int ct = 0; ct < CT; ++ct) { accp[ct] = (f32x4)0.0f; accq[ct] = (f32x4)0.0f; }

#pragma unroll
    for (int kk = 0; kk < 128; kk += 32) {
        short8 b;                            // B-frag: B[k][n=lane&15] = x[node][k]
        if (F32IN) {
            const float* xf = (const float*)xin + arow * 128 + kk + quad * 8;
            float4 f0 = *(const float4*)xf;
            float4 f1 = *(const float4*)(xf + 4);
            b[0] = (short)f2bf(f0.x); b[1] = (short)f2bf(f0.y);
            b[2] = (short)f2bf(f0.z); b[3] = (short)f2bf(f0.w);
            b[4] = (short)f2bf(f1.x); b[5] = (short)f2bf(f1.y);
            b[6] = (short)f2bf(f1.z); b[7] = (short)f2bf(f1.w);
        } else {
            b = *(const short8*)((const ushort*)xin + arow * 128 + kk + quad * 8);
        }
        int kc = (kk >> 3) + quad;
#pragma unroll
        for (int ct = 0; ct < CT; ++ct) {
            long boff = (((long)(ct * 16 + kc) * 16) + m) * 8;
            short8 al = *(const short8*)(Wfl + boff);   // A-frag (weights)
            short8 ar = *(const short8*)(Wfr + boff);
            accp[ct] = __builtin_amdgcn_mfma_f32_16x16x32_bf16(al, b, accp[ct], 0, 0, 0);
            accq[ct] = __builtin_amdgcn_mfma_f32_16x16x32_bf16(ar, b, accq[ct], 0, 0, 0);
        }
    }

    if (node < N) {
#pragma unroll
        for (int ct = 0; ct < CT; ++ct) {
            int c0 = ct * 16 + quad * 4;
            float4 bv = *(const float4*)(bias + c0);
            float q0 = accq[ct][0] + bv.x, q1 = accq[ct][1] + bv.y;
            float q2 = accq[ct][2] + bv.z, q3 = accq[ct][3] + bv.w;
            unsigned w = (unsigned)__builtin_amdgcn_cvt_pk_fp8_f32(accp[ct][0], accp[ct][1], 0, false);
            w = (unsigned)__builtin_amdgcn_cvt_pk_fp8_f32(accp[ct][2], accp[ct][3], (int)w, true);
            *(unsigned*)(p8 + node * COLS + c0) = w;
            uint2 qw; qw.x = pk4bf(q0, q1); qw.y = pk4bf(q2, q3);
            *(uint2*)(q + node * COLS + c0) = qw;
        }
    }
}

// ---------- layer-1 aggregate: h = bf16(relu(mean_nbr(p) + q)) ---------------------
// One wave per node; 16 lanes per edge, 8B/lane: one instr = 4 rows (512B).
// Unroll 16 edges -> 4 row loads in flight. Final 2-round shfl_xor column merge.
__global__ void agg_relu_kernel(const unsigned char* __restrict__ p8,  // N x 128 fp8
                                const ushort* __restrict__ q,          // N x 128 bf16
                                const int* __restrict__ ssrc,
                                const int* __restrict__ row_start,
                                const int* __restrict__ deg,
                                const float* __restrict__ inv_deg,
                                ushort* __restrict__ hb, int N) {
    int wave = threadIdx.x >> 6, lane = threadIdx.x & 63;
    int n = blockIdx.x * 4 + wave;
    if (n >= N) return;
    int g = lane >> 4, lm = lane & 15;             // edge slot / cols lm*8..lm*8+7
    int start = row_start[n], d = deg[n];
    const int* sp = ssrc + start;
    const unsigned char* pb = p8 + lm * 8;
    float a[8] = {};
    int j = 0;
    for (; j + 16 <= d; j += 16) {                 // 4 row loads = 16 edges in flight
        int s0 = sp[j + g], s1 = sp[j + 4 + g], s2 = sp[j + 8 + g], s3 = sp[j + 12 + g];
        uint2 v0 = *(const uint2*)(pb + (long)s0 * 128);
        uint2 v1 = *(const uint2*)(pb + (long)s1 * 128);
        uint2 v2 = *(const uint2*)(pb + (long)s2 * 128);
        uint2 v3 = *(const uint2*)(pb + (long)s3 * 128);
#pragma unroll
        for (int t = 0; t < 4; ++t) {
            uint2 vv = (t == 0) ? v0 : (t == 1) ? v1 : (t == 2) ? v2 : v3;
            f32x2 c0 = __builtin_amdgcn_cvt_pk_f32_fp8((int)vv.x, false);
            f32x2 c1 = __builtin_amdgcn_cvt_pk_f32_fp8((int)vv.x, true);
            f32x2 c2 = __builtin_amdgcn_cvt_pk_f32_fp8((int)vv.y, false);
            f32x2 c3 = __builtin_amdgcn_cvt_pk_f32_fp8((int)vv.y, true);
            a[0] += c0[0]; a[1] += c0[1]; a[2] += c1[0]; a[3] += c1[1];
            a[4] += c2[0]; a[5] += c2[1]; a[6] += c3[0]; a[7] += c3[1];
        }
    }
    for (; j < d; j += 4) {                        // predicated tail, 4 edges/iter
        int idx = j + g;
        int s = sp[idx < d ? idx : j];
        uint2 vv = *(const uint2*)(pb + (long)s * 128);
        if (idx < d) {
            f32x2 c0 = __builtin_amdgcn_cvt_pk_f32_fp8((int)vv.x, false);
            f32x2 c1 = __builtin_amdgcn_cvt_pk_f32_fp8((int)vv.x, true);
            f32x2 c2 = __builtin_amdgcn_cvt_pk_f32_fp8((int)vv.y, false);
            f32x2 c3 = __builtin_amdgcn_cvt_pk_f32_fp8((int)vv.y, true);
            a[0] += c0[0]; a[1] += c0[1]; a[2] += c1[0]; a[3] += c1[1];
            a[4] += c2[0]; a[5] += c2[1]; a[6] += c3[0]; a[7] += c3[1];
        }
    }
#pragma unroll
    for (int t = 0; t < 8; ++t) {                  // merge the 4 edge slots
        a[t] += __shfl_xor(a[t], 16);
        a[t] += __shfl_xor(a[t], 32);
    }
    if (g == 0) {                                  // 16 lanes store 8 cols each
        float iv = inv_deg[n];
        uint4 qv = *(const uint4*)(q + (long)n * 128 + lm * 8);
        float h0 = fmaxf(a[0] * iv + bflo(qv.x), 0.f);
        float h1 = fmaxf(a[1] * iv + bfhi(qv.x), 0.f);
        float h2 = fmaxf(a[2] * iv + bflo(qv.y), 0.f);
        float h3 = fmaxf(a[3] * iv + bfhi(qv.y), 0.f);
        float h4 = fmaxf(a[4] * iv + bflo(qv.z), 0.f);
        float h5 = fmaxf(a[5] * iv + bfhi(qv.z), 0.f);
        float h6 = fmaxf(a[6] * iv + bflo(qv.w), 0.f);
        float h7 = fmaxf(a[7] * iv + bfhi(qv.w), 0.f);
        uint4 hw;
        hw.x = pk4bf(h0, h1); hw.y = pk4bf(h2, h3);
        hw.z = pk4bf(h4, h5); hw.w = pk4bf(h6, h7);
        *(uint4*)(hb + (long)n * 128 + lm * 8) = hw;
    }
}

// ---------- layer-2 aggregate + log_softmax ----------------------------------------
// One wave per node; 8 lanes per edge, 8B/lane: one instr = 8 rows (512B).
__global__ void agg_lsm_kernel(const unsigned char* __restrict__ u8,   // N x 64 fp8
                               const ushort* __restrict__ v,           // N x 64 bf16
                               const int* __restrict__ ssrc,
                               const int* __restrict__ row_start,
                               const int* __restrict__ deg,
                               const float* __restrict__ inv_deg,
                               float* __restrict__ out, int N) {
    int wave = threadIdx.x >> 6, lane = threadIdx.x & 63;
    int n = blockIdx.x * 4 + wave;
    if (n >= N) return;
    int g = lane >> 3, lm = lane & 7;              // edge slot / cols lm*8..lm*8+7
    int start = row_start[n], d = deg[n];
    const int* sp = ssrc + start;
    const unsigned char* ub = u8 + lm * 8;
    float a[8] = {};
    int j = 0;
    for (; j + 16 <= d; j += 16) {                 // 2 row loads = 16 edges in flight
        int s0 = sp[j + g], s1 = sp[j + 8 + g];
        uint2 v0 = *(const uint2*)(ub + (long)s0 * 64);
        uint2 v1 = *(const uint2*)(ub + (long)s1 * 64);
#pragma unroll
        for (int t = 0; t < 2; ++t) {
            uint2 vv = (t == 0) ? v0 : v1;
            f32x2 c0 = __builtin_amdgcn_cvt_pk_f32_fp8((int)vv.x, false);
            f32x2 c1 = __builtin_amdgcn_cvt_pk_f32_fp8((int)vv.x, true);
            f32x2 c2 = __builtin_amdgcn_cvt_pk_f32_fp8((int)vv.y, false);
            f32x2 c3 = __builtin_amdgcn_cvt_pk_f32_fp8((int)vv.y, true);
            a[0] += c0[0]; a[1] += c0[1]; a[2] += c1[0]; a[3] += c1[1];
            a[4] += c2[0]; a[5] += c2[1]; a[6] += c3[0]; a[7] += c3[1];
        }
    }
    for (; j < d; j += 8) {                        // predicated tail, 8 edges/iter
        int idx = j + g;
        int s = sp[idx < d ? idx : j];
        uint2 vv = *(const uint2*)(ub + (long)s * 64);
        if (idx < d) {
            f32x2 c0 = __builtin_amdgcn_cvt_pk_f32_fp8((int)vv.x, false);
            f32x2 c1 = __builtin_amdgcn_cvt_pk_f32_fp8((int)vv.x, true);
            f32x2 c2 = __builtin_amdgcn_cvt_pk_f32_fp8((int)vv.y, false);
            f32x2 c3 = __builtin_amdgcn_cvt_pk_f32_fp8((int)vv.y, true);
            a[0] += c0[0]; a[1] += c0[1]; a[2] += c1[0]; a[3] += c1[1];
            a[4] += c2[0]; a[5] += c2[1]; a[6] += c3[0]; a[7] += c3[1];
        }
    }
#pragma unroll
    for (int t = 0; t < 8; ++t) {                  // merge the 8 edge slots
        a[t] += __shfl_xor(a[t], 8);
        a[t] += __shfl_xor(a[t], 16);
        a[t] += __shfl_xor(a[t], 32);
    }
    float iv = inv_deg[n];
    uint4 vv = *(const uint4*)(v + (long)n * 64 + lm * 8);
    float z0 = a[0] * iv + bflo(vv.x), z1 = a[1] * iv + bfhi(vv.x);
    float z2 = a[2] * iv + bflo(vv.y), z3 = a[3] * iv + bfhi(vv.y);
    float z4 = a[4] * iv + bflo(vv.z), z5 = a[5] * iv + bfhi(vv.z);
    float z6 = a[6] * iv + bflo(vv.w), z7 = a[7] * iv + bfhi(vv.w);
    float mx = fmaxf(fmaxf(fmaxf(z0, z1), fmaxf(z2, z3)),
                     fmaxf(fmaxf(z4, z5), fmaxf(z6, z7)));
#pragma unroll
    for (int o = 4; o > 0; o >>= 1) mx = fmaxf(mx, __shfl_xor(mx, o));   // over lm bits
    float e = (__expf(z0 - mx) + __expf(z1 - mx)) + (__expf(z2 - mx) + __expf(z3 - mx)) +
              (__expf(z4 - mx) + __expf(z5 - mx)) + (__expf(z6 - mx) + __expf(z7 - mx));
#pragma unroll
    for (int o = 4; o > 0; o >>= 1) e += __shfl_xor(e, o);
    float ls = mx + __logf(e);
    if (g == 0) {                                  // 8 lanes store 8 floats each
        float4 o0, o1;
        o0.x = z0 - ls; o0.y = z1 - ls; o0.z = z2 - ls; o0.w = z3 - ls;
        o1.x = z4 - ls; o1.y = z5 - ls; o1.z = z6 - ls; o1.w = z7 - ls;
        *(float4*)(out + (long)n * 64 + lm * 8) = o0;
        *(float4*)(out + (long)n * 64 + lm * 8 + 4) = o1;
    }
}

// -----------------------------------------------------------------------------------
extern "C" void kernel_launch(void* const* d_in, const int* in_sizes, int n_in,
                              void* d_out, int out_size, void* d_ws, size_t ws_size,
                              hipStream_t stream) {
    const float* x   = (const float*)d_in[0];
    const int*   ei  = (const int*)d_in[1];
    const float* Wl1 = (const float*)d_in[2];
    const float* Wr1 = (const float*)d_in[3];
    const float* b1  = (const float*)d_in[4];
    const float* Wl2 = (const float*)d_in[5];
    const float* Wr2 = (const float*)d_in[6];
    const float* b2  = (const float*)d_in[7];

    const int N = in_sizes[0] / 128;
    const int E = in_sizes[1] / 2;
    const int* src = ei;
    const int* dst = ei + E;
    const int NB = (N + NPB - 1) / NPB;

    size_t off = 0;
    auto take = [&](size_t nbytes) -> void* {
        void* ptr = (void*)((char*)d_ws + off);
        off += (nbytes + 255) & ~(size_t)255;
        return ptr;
    };
    int*      bcount    = (int*)take((size_t)NB * 4);
    int*      bbase     = (int*)take((size_t)NB * 4);
    unsigned* bbuf      = (unsigned*)take((size_t)NB * BCAP * 4);   // 12.8 MB
    int*      row_start = (int*)take((size_t)N * 4);
    int*      degw      = (int*)take((size_t)N * 4);
    float*    inv_deg   = (float*)take((size_t)N * 4);
    int*      ssrc      = (int*)take((size_t)E * 4);
    unsigned char* p8   = (unsigned char*)take((size_t)N * 128);    // reused as u8
    ushort*   q         = (ushort*)take((size_t)N * 128 * 2);       // reused as v
    ushort*   hb        = (ushort*)take((size_t)N * 128 * 2);
    ushort*   Wf_l1     = (ushort*)take(128 * 128 * 2);
    ushort*   Wf_r1     = (ushort*)take(128 * 128 * 2);
    ushort*   Wf_l2     = (ushort*)take(64 * 128 * 2);
    ushort*   Wf_r2     = (ushort*)take(64 * 128 * 2);
    unsigned char* u8 = p8;   // p dead after agg_relu
    ushort*        v  = q;    // q dead after agg_relu
    (void)ws_size; (void)n_in; (void)out_size;

    hipMemsetAsync(bcount, 0, (size_t)NB * 4, stream);

    bucket_scatter<<<(E + CHUNK - 1) / CHUNK, 256, 0, stream>>>(src, dst, bcount, bbuf, E, NB);
    scan_buckets  <<<1, 256, 0, stream>>>(bcount, bbase, NB);
    build_csr     <<<NB, 256, 0, stream>>>(bbuf, bcount, bbase, row_start, degw, inv_deg, ssrc, N);
    cvt_w_kernel  <<<192, 256, 0, stream>>>(Wl1, Wr1, Wl2, Wr2, Wf_l1, Wf_r1, Wf_l2, Wf_r2);

    // layer 1
    proj_kernel<128, true><<<(N + 63) / 64, 256, 0, stream>>>(x, Wf_l1, Wf_r1, b1, p8, q, N);
    agg_relu_kernel<<<(N + 3) / 4, 256, 0, stream>>>(p8, q, ssrc, row_start, degw, inv_deg, hb, N);

    // layer 2 (aggregate in 64-wide projected fp8 space)
    proj_kernel<64, false><<<(N + 63) / 64, 256, 0, stream>>>(hb, Wf_l2, Wf_r2, b2, u8, v, N);
    agg_lsm_kernel<<<(N + 3) / 4, 256, 0, stream>>>(u8, v, ssrc, row_start, degw, inv_deg,
                                                    (float*)d_out, N);
}